// Round 2
// baseline (210.726 us; speedup 1.0000x reference)
//
#include <hip/hip_runtime.h>
#include <math.h>

// LaplacianBuilder: N=2048 nodes, DEG=16, D=4, E=32768 edges (2E=65536 directed)
// out = dense (8192 x 8192) fp32, 256 MB. Strategy: compute compact block
// values + per-node adjacency, then ONE streaming writer pass (no memset of out).

#define NNODES 2048
#define MAXDEG 96   // per-node adjacency capacity (expected 32, ~11 sigma margin)

// ---------------------------------------------------------------------------
// Kernel 1: accumulate per-node Gram matrices  diag[node] += M_e^T M_e
// ---------------------------------------------------------------------------
__global__ void accum_diag_kernel(const float* __restrict__ maps,
                                  const int* __restrict__ row_all,
                                  float* __restrict__ diag,
                                  int twoE) {
    int e = blockIdx.x * blockDim.x + threadIdx.x;
    if (e >= twoE) return;
    const float4* mp = reinterpret_cast<const float4*>(maps + (size_t)e * 16);
    float4 q0 = mp[0], q1 = mp[1], q2 = mp[2], q3 = mp[3];
    float m[4][4] = {
        {q0.x, q0.y, q0.z, q0.w},
        {q1.x, q1.y, q1.z, q1.w},
        {q2.x, q2.y, q2.z, q2.w},
        {q3.x, q3.y, q3.z, q3.w},
    };
    int node = row_all[e];
    float* dst = diag + (size_t)node * 16;
    #pragma unroll
    for (int i = 0; i < 4; ++i) {
        #pragma unroll
        for (int j = i; j < 4; ++j) {
            float cc = m[0][i] * m[0][j] + m[1][i] * m[1][j] +
                       m[2][i] * m[2][j] + m[3][i] * m[3][j];
            atomicAdd(dst + i * 4 + j, cc);
            if (i != j) atomicAdd(dst + j * 4 + i, cc);
        }
    }
}

// ---------------------------------------------------------------------------
// Jacobi rotation on (P,Q), compile-time indices -> stays in registers
// ---------------------------------------------------------------------------
template <int P, int Q>
__device__ __forceinline__ void jrot(float a[4][4], float v[4][4]) {
    float apq = a[P][Q];
    if (fabsf(apq) < 1e-12f) return;
    float theta = (a[Q][Q] - a[P][P]) / (2.0f * apq);
    float t = 1.0f / (fabsf(theta) + sqrtf(theta * theta + 1.0f));
    t = (theta < 0.0f) ? -t : t;
    float c = 1.0f / sqrtf(t * t + 1.0f);
    float s = t * c;
    #pragma unroll
    for (int k = 0; k < 4; ++k) {
        float akp = a[k][P], akq = a[k][Q];
        a[k][P] = c * akp - s * akq;
        a[k][Q] = s * akp + c * akq;
    }
    #pragma unroll
    for (int k = 0; k < 4; ++k) {
        float apk = a[P][k], aqk = a[Q][k];
        a[P][k] = c * apk - s * aqk;
        a[Q][k] = s * apk + c * aqk;
    }
    #pragma unroll
    for (int k = 0; k < 4; ++k) {
        float vkp = v[k][P], vkq = v[k][Q];
        v[k][P] = c * vkp - s * vkq;
        v[k][Q] = s * vkp + c * vkq;
    }
}

// ---------------------------------------------------------------------------
// Kernel 2: per node, eigh(D + I) -> S = (D+I)^(-1/2); store S and the
// clipped diagonal block  vdiag = clip(S D S, -1, 1)  (compact, not to out)
// ---------------------------------------------------------------------------
__global__ void node_kernel(const float* __restrict__ diag,
                            float* __restrict__ Smat,
                            float* __restrict__ vdiag,
                            int n) {
    int node = blockIdx.x * blockDim.x + threadIdx.x;
    if (node >= n) return;
    const float4* dp = reinterpret_cast<const float4*>(diag + (size_t)node * 16);
    float4 q0 = dp[0], q1 = dp[1], q2 = dp[2], q3 = dp[3];
    float dmat[4][4] = {
        {q0.x, q0.y, q0.z, q0.w},
        {q1.x, q1.y, q1.z, q1.w},
        {q2.x, q2.y, q2.z, q2.w},
        {q3.x, q3.y, q3.z, q3.w},
    };
    float a[4][4], v[4][4];
    #pragma unroll
    for (int i = 0; i < 4; ++i) {
        #pragma unroll
        for (int j = 0; j < 4; ++j) {
            a[i][j] = dmat[i][j] + (i == j ? 1.0f : 0.0f);
            v[i][j] = (i == j) ? 1.0f : 0.0f;
        }
    }
    #pragma unroll
    for (int sweep = 0; sweep < 6; ++sweep) {
        jrot<0, 1>(a, v); jrot<0, 2>(a, v); jrot<0, 3>(a, v);
        jrot<1, 2>(a, v); jrot<1, 3>(a, v); jrot<2, 3>(a, v);
    }
    float ir[4];
    #pragma unroll
    for (int m = 0; m < 4; ++m)
        ir[m] = 1.0f / sqrtf(fmaxf(a[m][m], 1e-8f));
    float s[4][4];
    #pragma unroll
    for (int i = 0; i < 4; ++i)
        #pragma unroll
        for (int j = 0; j < 4; ++j)
            s[i][j] = v[i][0] * v[j][0] * ir[0] + v[i][1] * v[j][1] * ir[1] +
                      v[i][2] * v[j][2] * ir[2] + v[i][3] * v[j][3] * ir[3];
    float4* sp = reinterpret_cast<float4*>(Smat + (size_t)node * 16);
    sp[0] = make_float4(s[0][0], s[0][1], s[0][2], s[0][3]);
    sp[1] = make_float4(s[1][0], s[1][1], s[1][2], s[1][3]);
    sp[2] = make_float4(s[2][0], s[2][1], s[2][2], s[2][3]);
    sp[3] = make_float4(s[3][0], s[3][1], s[3][2], s[3][3]);
    float t1[4][4];
    #pragma unroll
    for (int i = 0; i < 4; ++i)
        #pragma unroll
        for (int j = 0; j < 4; ++j)
            t1[i][j] = s[i][0] * dmat[0][j] + s[i][1] * dmat[1][j] +
                       s[i][2] * dmat[2][j] + s[i][3] * dmat[3][j];
    float4* vp = reinterpret_cast<float4*>(vdiag + (size_t)node * 16);
    #pragma unroll
    for (int i = 0; i < 4; ++i) {
        float r0 = t1[i][0] * s[0][0] + t1[i][1] * s[1][0] + t1[i][2] * s[2][0] + t1[i][3] * s[3][0];
        float r1 = t1[i][0] * s[0][1] + t1[i][1] * s[1][1] + t1[i][2] * s[2][1] + t1[i][3] * s[3][1];
        float r2 = t1[i][0] * s[0][2] + t1[i][1] * s[1][2] + t1[i][2] * s[2][2] + t1[i][3] * s[3][2];
        float r3 = t1[i][0] * s[0][3] + t1[i][1] * s[1][3] + t1[i][2] * s[2][3] + t1[i][3] * s[3][3];
        vp[i] = make_float4(fminf(fmaxf(r0, -1.0f), 1.0f),
                            fminf(fmaxf(r1, -1.0f), 1.0f),
                            fminf(fmaxf(r2, -1.0f), 1.0f),
                            fminf(fmaxf(r3, -1.0f), 1.0f));
    }
}

// ---------------------------------------------------------------------------
// Kernel 3: per edge, W = -clip(S_r (A^T B) S_c, -1, 1); store W compactly and
// append adjacency entries:
//   node r gets (col=c, e, t=0)  [reference scatter L[r,c] = W]
//   node c gets (col=r, e, t=1)  [reference scatter L[c,r] = W^T — wins ties]
// Entry pack: col<<20 | t<<19 | e  (col<2048, e<32768). Append order is
// nondeterministic but the writer resolves duplicates by preferring t=1,
// which is unique per (node,col) -> deterministic output.
// ---------------------------------------------------------------------------
__global__ void edge_kernel(const float* __restrict__ maps,
                            const int* __restrict__ ei,
                            const float* __restrict__ Smat,
                            float* __restrict__ vedge,
                            int* __restrict__ lists,
                            int* __restrict__ cnts,
                            int E, int twoE) {
    int e = blockIdx.x * blockDim.x + threadIdx.x;
    if (e >= E) return;
    int r = ei[e];
    int c = ei[twoE + e];
    const float4* ap = reinterpret_cast<const float4*>(maps + (size_t)e * 16);
    const float4* bp = reinterpret_cast<const float4*>(maps + (size_t)(E + e) * 16);
    float4 a0 = ap[0], a1 = ap[1], a2 = ap[2], a3 = ap[3];
    float4 b0 = bp[0], b1 = bp[1], b2 = bp[2], b3 = bp[3];
    float A[4][4] = {{a0.x, a0.y, a0.z, a0.w}, {a1.x, a1.y, a1.z, a1.w},
                     {a2.x, a2.y, a2.z, a2.w}, {a3.x, a3.y, a3.z, a3.w}};
    float B[4][4] = {{b0.x, b0.y, b0.z, b0.w}, {b1.x, b1.y, b1.z, b1.w},
                     {b2.x, b2.y, b2.z, b2.w}, {b3.x, b3.y, b3.z, b3.w}};
    float C[4][4];
    #pragma unroll
    for (int i = 0; i < 4; ++i)
        #pragma unroll
        for (int j = 0; j < 4; ++j)
            C[i][j] = A[0][i] * B[0][j] + A[1][i] * B[1][j] +
                      A[2][i] * B[2][j] + A[3][i] * B[3][j];
    const float4* srp = reinterpret_cast<const float4*>(Smat + (size_t)r * 16);
    const float4* scp = reinterpret_cast<const float4*>(Smat + (size_t)c * 16);
    float4 s0 = srp[0], s1 = srp[1], s2 = srp[2], s3 = srp[3];
    float Sr[4][4] = {{s0.x, s0.y, s0.z, s0.w}, {s1.x, s1.y, s1.z, s1.w},
                      {s2.x, s2.y, s2.z, s2.w}, {s3.x, s3.y, s3.z, s3.w}};
    float4 c0 = scp[0], c1 = scp[1], c2 = scp[2], c3 = scp[3];
    float Sc[4][4] = {{c0.x, c0.y, c0.z, c0.w}, {c1.x, c1.y, c1.z, c1.w},
                      {c2.x, c2.y, c2.z, c2.w}, {c3.x, c3.y, c3.z, c3.w}};
    float t1[4][4];
    #pragma unroll
    for (int i = 0; i < 4; ++i)
        #pragma unroll
        for (int j = 0; j < 4; ++j)
            t1[i][j] = Sr[i][0] * C[0][j] + Sr[i][1] * C[1][j] +
                       Sr[i][2] * C[2][j] + Sr[i][3] * C[3][j];
    float4* wp = reinterpret_cast<float4*>(vedge + (size_t)e * 16);
    #pragma unroll
    for (int i = 0; i < 4; ++i) {
        float w0 = t1[i][0] * Sc[0][0] + t1[i][1] * Sc[1][0] + t1[i][2] * Sc[2][0] + t1[i][3] * Sc[3][0];
        float w1 = t1[i][0] * Sc[0][1] + t1[i][1] * Sc[1][1] + t1[i][2] * Sc[2][1] + t1[i][3] * Sc[3][1];
        float w2 = t1[i][0] * Sc[0][2] + t1[i][1] * Sc[1][2] + t1[i][2] * Sc[2][2] + t1[i][3] * Sc[3][2];
        float w3 = t1[i][0] * Sc[0][3] + t1[i][1] * Sc[1][3] + t1[i][2] * Sc[2][3] + t1[i][3] * Sc[3][3];
        wp[i] = make_float4(-fminf(fmaxf(w0, -1.0f), 1.0f),
                            -fminf(fmaxf(w1, -1.0f), 1.0f),
                            -fminf(fmaxf(w2, -1.0f), 1.0f),
                            -fminf(fmaxf(w3, -1.0f), 1.0f));
    }
    int sr = atomicAdd(&cnts[r], 1);
    if (sr < MAXDEG) lists[(size_t)r * MAXDEG + sr] = (c << 20) | e;
    int sc = atomicAdd(&cnts[c], 1);
    if (sc < MAXDEG) lists[(size_t)c * MAXDEG + sc] = (r << 20) | (1 << 19) | e;
}

// ---------------------------------------------------------------------------
// Kernel 4: streaming writer. One workgroup per node block-row r; writes all
// 4 x 8192 floats (128 KB) of that block-row: zeros except diag block and
// adjacency blocks (bitmap test in LDS; rare hits scan the short list,
// preferring t=1 entries to reproduce reference overwrite order).
// ---------------------------------------------------------------------------
__global__ void __launch_bounds__(256)
writer_kernel(const int* __restrict__ lists,
              const int* __restrict__ cnts,
              const float* __restrict__ vdiag,
              const float* __restrict__ vedge,
              float* __restrict__ out, int ld) {
    int r = blockIdx.x;
    int tid = threadIdx.x;
    __shared__ unsigned int bm[64];          // 2048-bit column bitmap
    __shared__ int s_col[MAXDEG];            // (col<<1)|t
    __shared__ float4 s_dat[MAXDEG][4];      // block rows (transpose applied)
    __shared__ float4 s_diag[4];
    if (tid < 64) bm[tid] = 0u;
    __syncthreads();
    int cnt = cnts[r];
    if (cnt > MAXDEG) cnt = MAXDEG;
    if (tid < cnt) {
        int entry = lists[(size_t)r * MAXDEG + tid];
        int col = entry >> 20;
        int t = (entry >> 19) & 1;
        int e = entry & 0x7FFF;
        s_col[tid] = (col << 1) | t;
        const float4* vp = reinterpret_cast<const float4*>(vedge + (size_t)e * 16);
        float4 v0 = vp[0], v1 = vp[1], v2 = vp[2], v3 = vp[3];
        if (t) {
            s_dat[tid][0] = make_float4(v0.x, v1.x, v2.x, v3.x);
            s_dat[tid][1] = make_float4(v0.y, v1.y, v2.y, v3.y);
            s_dat[tid][2] = make_float4(v0.z, v1.z, v2.z, v3.z);
            s_dat[tid][3] = make_float4(v0.w, v1.w, v2.w, v3.w);
        } else {
            s_dat[tid][0] = v0; s_dat[tid][1] = v1;
            s_dat[tid][2] = v2; s_dat[tid][3] = v3;
        }
        atomicOr(&bm[col >> 5], 1u << (col & 31));
    }
    if (tid < 4)
        s_diag[tid] = reinterpret_cast<const float4*>(vdiag + (size_t)r * 16)[tid];
    __syncthreads();
    size_t base = (size_t)(r * 4) * (size_t)ld;
    const float4 zero = make_float4(0.f, 0.f, 0.f, 0.f);
    #pragma unroll
    for (int ri = 0; ri < 4; ++ri) {
        float4* orow = reinterpret_cast<float4*>(out + base + (size_t)ri * ld);
        for (int cb = tid; cb < NNODES; cb += 256) {
            float4 val = zero;
            if (cb == r) {
                val = s_diag[ri];
            } else if (bm[cb >> 5] & (1u << (cb & 31))) {
                int best = -1;
                for (int j = 0; j < cnt; ++j)
                    if ((s_col[j] >> 1) == cb && (best < 0 || (s_col[j] & 1)))
                        best = j;
                val = s_dat[best][ri];
            }
            orow[cb] = val;
        }
    }
}

extern "C" void kernel_launch(void* const* d_in, const int* in_sizes, int n_in,
                              void* d_out, int out_size, void* d_ws, size_t ws_size,
                              hipStream_t stream) {
    const float* maps = (const float*)d_in[0];
    const int* ei = (const int*)d_in[1];   // (2, 2E) int32
    int twoE = in_sizes[0] / 16;           // 65536
    int E = twoE / 2;                      // 32768
    const int n = NNODES;
    const int ld = n * 4;                  // 8192
    float* out = (float*)d_out;

    // workspace layout (floats unless noted)
    float* ws_diag = (float*)d_ws;                       // n*16
    float* ws_S    = ws_diag + (size_t)n * 16;           // n*16
    float* ws_vd   = ws_S    + (size_t)n * 16;           // n*16
    float* ws_ve   = ws_vd   + (size_t)n * 16;           // E*16 (2 MB)
    int*   ws_cnt  = (int*)(ws_ve + (size_t)E * 16);     // n ints
    int*   ws_list = ws_cnt + n;                         // n*MAXDEG ints

    hipMemsetAsync(ws_diag, 0, (size_t)n * 16 * sizeof(float), stream);
    hipMemsetAsync(ws_cnt, 0, (size_t)n * sizeof(int), stream);

    accum_diag_kernel<<<(twoE + 255) / 256, 256, 0, stream>>>(maps, ei, ws_diag, twoE);
    node_kernel<<<(n + 255) / 256, 256, 0, stream>>>(ws_diag, ws_S, ws_vd, n);
    edge_kernel<<<(E + 255) / 256, 256, 0, stream>>>(maps, ei, ws_S, ws_ve,
                                                     ws_list, ws_cnt, E, twoE);
    writer_kernel<<<n, 256, 0, stream>>>(ws_list, ws_cnt, ws_vd, ws_ve, out, ld);
}

// Round 3
// 128.010 us; speedup vs baseline: 1.6462x; 1.6462x over previous
//
#include <hip/hip_runtime.h>
#include <math.h>

// LaplacianBuilder: N=2048 nodes, DEG=16, D=4, E=32768 edges (2E=65536 directed)
// out = dense (8192 x 8192) fp32, 256 MB. Strategy: compute compact block
// values + per-node adjacency, then ONE streaming writer pass with an O(1)
// LDS column->slot map (no memset of out, no per-column list scan).

#define NNODES 2048
#define MAXDEG 96   // per-node adjacency capacity (expected 32, huge margin)

// ---------------------------------------------------------------------------
// Kernel 1: accumulate per-node Gram matrices  diag[node] += M_e^T M_e
// ---------------------------------------------------------------------------
__global__ void accum_diag_kernel(const float* __restrict__ maps,
                                  const int* __restrict__ row_all,
                                  float* __restrict__ diag,
                                  int twoE) {
    int e = blockIdx.x * blockDim.x + threadIdx.x;
    if (e >= twoE) return;
    const float4* mp = reinterpret_cast<const float4*>(maps + (size_t)e * 16);
    float4 q0 = mp[0], q1 = mp[1], q2 = mp[2], q3 = mp[3];
    float m[4][4] = {
        {q0.x, q0.y, q0.z, q0.w},
        {q1.x, q1.y, q1.z, q1.w},
        {q2.x, q2.y, q2.z, q2.w},
        {q3.x, q3.y, q3.z, q3.w},
    };
    int node = row_all[e];
    float* dst = diag + (size_t)node * 16;
    #pragma unroll
    for (int i = 0; i < 4; ++i) {
        #pragma unroll
        for (int j = i; j < 4; ++j) {
            float cc = m[0][i] * m[0][j] + m[1][i] * m[1][j] +
                       m[2][i] * m[2][j] + m[3][i] * m[3][j];
            atomicAdd(dst + i * 4 + j, cc);
            if (i != j) atomicAdd(dst + j * 4 + i, cc);
        }
    }
}

// ---------------------------------------------------------------------------
// Jacobi rotation on (P,Q), compile-time indices -> stays in registers
// ---------------------------------------------------------------------------
template <int P, int Q>
__device__ __forceinline__ void jrot(float a[4][4], float v[4][4]) {
    float apq = a[P][Q];
    if (fabsf(apq) < 1e-12f) return;
    float theta = (a[Q][Q] - a[P][P]) / (2.0f * apq);
    float t = 1.0f / (fabsf(theta) + sqrtf(theta * theta + 1.0f));
    t = (theta < 0.0f) ? -t : t;
    float c = 1.0f / sqrtf(t * t + 1.0f);
    float s = t * c;
    #pragma unroll
    for (int k = 0; k < 4; ++k) {
        float akp = a[k][P], akq = a[k][Q];
        a[k][P] = c * akp - s * akq;
        a[k][Q] = s * akp + c * akq;
    }
    #pragma unroll
    for (int k = 0; k < 4; ++k) {
        float apk = a[P][k], aqk = a[Q][k];
        a[P][k] = c * apk - s * aqk;
        a[Q][k] = s * apk + c * aqk;
    }
    #pragma unroll
    for (int k = 0; k < 4; ++k) {
        float vkp = v[k][P], vkq = v[k][Q];
        v[k][P] = c * vkp - s * vkq;
        v[k][Q] = s * vkp + c * vkq;
    }
}

// ---------------------------------------------------------------------------
// Kernel 2: per node, eigh(D + I) -> S = (D+I)^(-1/2); store S and the
// clipped diagonal block  vdiag = clip(S D S, -1, 1)  (compact)
// ---------------------------------------------------------------------------
__global__ void node_kernel(const float* __restrict__ diag,
                            float* __restrict__ Smat,
                            float* __restrict__ vdiag,
                            int n) {
    int node = blockIdx.x * blockDim.x + threadIdx.x;
    if (node >= n) return;
    const float4* dp = reinterpret_cast<const float4*>(diag + (size_t)node * 16);
    float4 q0 = dp[0], q1 = dp[1], q2 = dp[2], q3 = dp[3];
    float dmat[4][4] = {
        {q0.x, q0.y, q0.z, q0.w},
        {q1.x, q1.y, q1.z, q1.w},
        {q2.x, q2.y, q2.z, q2.w},
        {q3.x, q3.y, q3.z, q3.w},
    };
    float a[4][4], v[4][4];
    #pragma unroll
    for (int i = 0; i < 4; ++i) {
        #pragma unroll
        for (int j = 0; j < 4; ++j) {
            a[i][j] = dmat[i][j] + (i == j ? 1.0f : 0.0f);
            v[i][j] = (i == j) ? 1.0f : 0.0f;
        }
    }
    #pragma unroll
    for (int sweep = 0; sweep < 6; ++sweep) {
        jrot<0, 1>(a, v); jrot<0, 2>(a, v); jrot<0, 3>(a, v);
        jrot<1, 2>(a, v); jrot<1, 3>(a, v); jrot<2, 3>(a, v);
    }
    float ir[4];
    #pragma unroll
    for (int m = 0; m < 4; ++m)
        ir[m] = 1.0f / sqrtf(fmaxf(a[m][m], 1e-8f));
    float s[4][4];
    #pragma unroll
    for (int i = 0; i < 4; ++i)
        #pragma unroll
        for (int j = 0; j < 4; ++j)
            s[i][j] = v[i][0] * v[j][0] * ir[0] + v[i][1] * v[j][1] * ir[1] +
                      v[i][2] * v[j][2] * ir[2] + v[i][3] * v[j][3] * ir[3];
    float4* sp = reinterpret_cast<float4*>(Smat + (size_t)node * 16);
    sp[0] = make_float4(s[0][0], s[0][1], s[0][2], s[0][3]);
    sp[1] = make_float4(s[1][0], s[1][1], s[1][2], s[1][3]);
    sp[2] = make_float4(s[2][0], s[2][1], s[2][2], s[2][3]);
    sp[3] = make_float4(s[3][0], s[3][1], s[3][2], s[3][3]);
    float t1[4][4];
    #pragma unroll
    for (int i = 0; i < 4; ++i)
        #pragma unroll
        for (int j = 0; j < 4; ++j)
            t1[i][j] = s[i][0] * dmat[0][j] + s[i][1] * dmat[1][j] +
                       s[i][2] * dmat[2][j] + s[i][3] * dmat[3][j];
    float4* vp = reinterpret_cast<float4*>(vdiag + (size_t)node * 16);
    #pragma unroll
    for (int i = 0; i < 4; ++i) {
        float r0 = t1[i][0] * s[0][0] + t1[i][1] * s[1][0] + t1[i][2] * s[2][0] + t1[i][3] * s[3][0];
        float r1 = t1[i][0] * s[0][1] + t1[i][1] * s[1][1] + t1[i][2] * s[2][1] + t1[i][3] * s[3][1];
        float r2 = t1[i][0] * s[0][2] + t1[i][1] * s[1][2] + t1[i][2] * s[2][2] + t1[i][3] * s[3][2];
        float r3 = t1[i][0] * s[0][3] + t1[i][1] * s[1][3] + t1[i][2] * s[2][3] + t1[i][3] * s[3][3];
        vp[i] = make_float4(fminf(fmaxf(r0, -1.0f), 1.0f),
                            fminf(fmaxf(r1, -1.0f), 1.0f),
                            fminf(fmaxf(r2, -1.0f), 1.0f),
                            fminf(fmaxf(r3, -1.0f), 1.0f));
    }
}

// ---------------------------------------------------------------------------
// Kernel 3: per edge, W = -clip(S_r (A^T B) S_c, -1, 1); store W compactly and
// append adjacency entries:
//   node r gets (col=c, e, t=0)  [reference scatter L[r,c] = W]
//   node c gets (col=r, e, t=1)  [reference scatter L[c,r] = W^T — wins ties]
// Entry pack: col<<20 | t<<19 | e. Append order nondeterministic; writer
// resolves (node,col) duplicates by letting t=1 overwrite t=0 -> deterministic.
// ---------------------------------------------------------------------------
__global__ void edge_kernel(const float* __restrict__ maps,
                            const int* __restrict__ ei,
                            const float* __restrict__ Smat,
                            float* __restrict__ vedge,
                            int* __restrict__ lists,
                            int* __restrict__ cnts,
                            int E, int twoE) {
    int e = blockIdx.x * blockDim.x + threadIdx.x;
    if (e >= E) return;
    int r = ei[e];
    int c = ei[twoE + e];
    const float4* ap = reinterpret_cast<const float4*>(maps + (size_t)e * 16);
    const float4* bp = reinterpret_cast<const float4*>(maps + (size_t)(E + e) * 16);
    float4 a0 = ap[0], a1 = ap[1], a2 = ap[2], a3 = ap[3];
    float4 b0 = bp[0], b1 = bp[1], b2 = bp[2], b3 = bp[3];
    float A[4][4] = {{a0.x, a0.y, a0.z, a0.w}, {a1.x, a1.y, a1.z, a1.w},
                     {a2.x, a2.y, a2.z, a2.w}, {a3.x, a3.y, a3.z, a3.w}};
    float B[4][4] = {{b0.x, b0.y, b0.z, b0.w}, {b1.x, b1.y, b1.z, b1.w},
                     {b2.x, b2.y, b2.z, b2.w}, {b3.x, b3.y, b3.z, b3.w}};
    float C[4][4];
    #pragma unroll
    for (int i = 0; i < 4; ++i)
        #pragma unroll
        for (int j = 0; j < 4; ++j)
            C[i][j] = A[0][i] * B[0][j] + A[1][i] * B[1][j] +
                      A[2][i] * B[2][j] + A[3][i] * B[3][j];
    const float4* srp = reinterpret_cast<const float4*>(Smat + (size_t)r * 16);
    const float4* scp = reinterpret_cast<const float4*>(Smat + (size_t)c * 16);
    float4 s0 = srp[0], s1 = srp[1], s2 = srp[2], s3 = srp[3];
    float Sr[4][4] = {{s0.x, s0.y, s0.z, s0.w}, {s1.x, s1.y, s1.z, s1.w},
                      {s2.x, s2.y, s2.z, s2.w}, {s3.x, s3.y, s3.z, s3.w}};
    float4 c0 = scp[0], c1 = scp[1], c2 = scp[2], c3 = scp[3];
    float Sc[4][4] = {{c0.x, c0.y, c0.z, c0.w}, {c1.x, c1.y, c1.z, c1.w},
                      {c2.x, c2.y, c2.z, c2.w}, {c3.x, c3.y, c3.z, c3.w}};
    float t1[4][4];
    #pragma unroll
    for (int i = 0; i < 4; ++i)
        #pragma unroll
        for (int j = 0; j < 4; ++j)
            t1[i][j] = Sr[i][0] * C[0][j] + Sr[i][1] * C[1][j] +
                       Sr[i][2] * C[2][j] + Sr[i][3] * C[3][j];
    float4* wp = reinterpret_cast<float4*>(vedge + (size_t)e * 16);
    #pragma unroll
    for (int i = 0; i < 4; ++i) {
        float w0 = t1[i][0] * Sc[0][0] + t1[i][1] * Sc[1][0] + t1[i][2] * Sc[2][0] + t1[i][3] * Sc[3][0];
        float w1 = t1[i][0] * Sc[0][1] + t1[i][1] * Sc[1][1] + t1[i][2] * Sc[2][1] + t1[i][3] * Sc[3][1];
        float w2 = t1[i][0] * Sc[0][2] + t1[i][1] * Sc[1][2] + t1[i][2] * Sc[2][2] + t1[i][3] * Sc[3][2];
        float w3 = t1[i][0] * Sc[0][3] + t1[i][1] * Sc[1][3] + t1[i][2] * Sc[2][3] + t1[i][3] * Sc[3][3];
        wp[i] = make_float4(-fminf(fmaxf(w0, -1.0f), 1.0f),
                            -fminf(fmaxf(w1, -1.0f), 1.0f),
                            -fminf(fmaxf(w2, -1.0f), 1.0f),
                            -fminf(fmaxf(w3, -1.0f), 1.0f));
    }
    int sr = atomicAdd(&cnts[r], 1);
    if (sr < MAXDEG) lists[(size_t)r * MAXDEG + sr] = (c << 20) | e;
    int sc = atomicAdd(&cnts[c], 1);
    if (sc < MAXDEG) lists[(size_t)c * MAXDEG + sc] = (r << 20) | (1 << 19) | e;
}

// ---------------------------------------------------------------------------
// Kernel 4: streaming writer. One workgroup per node block-row r; writes all
// 4 x 8192 floats (128 KB). O(1) lookup via LDS colmap[2048] (int slot, -1
// empty). t=0 entries write first, then t=1 overwrite (reference semantics).
// Diag block lives at slot MAXDEG. Inner loop: 1 LDS dword read + select +
// coalesced float4 store -> write-BW bound.
// ---------------------------------------------------------------------------
__global__ void __launch_bounds__(256)
writer_kernel(const int* __restrict__ lists,
              const int* __restrict__ cnts,
              const float* __restrict__ vdiag,
              const float* __restrict__ vedge,
              float* __restrict__ out, int ld) {
    int r = blockIdx.x;
    int tid = threadIdx.x;
    __shared__ int colmap[NNODES];             // 8 KB
    __shared__ float4 s_dat[MAXDEG + 1][4];    // ~6.2 KB
    for (int i = tid; i < NNODES; i += 256) colmap[i] = -1;

    int cnt = cnts[r];
    if (cnt > MAXDEG) cnt = MAXDEG;
    int col = -1, t = 0;
    if (tid < cnt) {
        int entry = lists[(size_t)r * MAXDEG + tid];
        col = entry >> 20;
        t = (entry >> 19) & 1;
        int e = entry & 0x7FFF;
        const float4* vp = reinterpret_cast<const float4*>(vedge + (size_t)e * 16);
        float4 v0 = vp[0], v1 = vp[1], v2 = vp[2], v3 = vp[3];
        if (t) {
            s_dat[tid][0] = make_float4(v0.x, v1.x, v2.x, v3.x);
            s_dat[tid][1] = make_float4(v0.y, v1.y, v2.y, v3.y);
            s_dat[tid][2] = make_float4(v0.z, v1.z, v2.z, v3.z);
            s_dat[tid][3] = make_float4(v0.w, v1.w, v2.w, v3.w);
        } else {
            s_dat[tid][0] = v0; s_dat[tid][1] = v1;
            s_dat[tid][2] = v2; s_dat[tid][3] = v3;
        }
    }
    if (tid < 4)
        s_dat[MAXDEG][tid] = reinterpret_cast<const float4*>(vdiag + (size_t)r * 16)[tid];
    __syncthreads();                 // colmap cleared + s_dat populated
    if (tid < cnt && !t) colmap[col] = tid;
    __syncthreads();                 // t=0 entries placed
    if (tid < cnt && t) colmap[col] = tid;   // t=1 wins (reference order)
    if (tid == 0) colmap[r] = MAXDEG;        // diag (no self-edges -> safe)
    __syncthreads();

    size_t base = (size_t)(r * 4) * (size_t)ld;
    const float4 zero = make_float4(0.f, 0.f, 0.f, 0.f);
    #pragma unroll
    for (int ri = 0; ri < 4; ++ri) {
        float4* orow = reinterpret_cast<float4*>(out + base + (size_t)ri * ld);
        for (int cb = tid; cb < NNODES; cb += 256) {
            int sl = colmap[cb];
            float4 val = zero;
            if (sl >= 0) val = s_dat[sl][ri];
            orow[cb] = val;
        }
    }
}

extern "C" void kernel_launch(void* const* d_in, const int* in_sizes, int n_in,
                              void* d_out, int out_size, void* d_ws, size_t ws_size,
                              hipStream_t stream) {
    const float* maps = (const float*)d_in[0];
    const int* ei = (const int*)d_in[1];   // (2, 2E) int32
    int twoE = in_sizes[0] / 16;           // 65536
    int E = twoE / 2;                      // 32768
    const int n = NNODES;
    const int ld = n * 4;                  // 8192
    float* out = (float*)d_out;

    // workspace layout: [diag n*16 f][cnt n i] contiguous (single memset),
    // then S, vdiag, vedge, lists.
    float* ws_diag = (float*)d_ws;                        // n*16 floats
    int*   ws_cnt  = (int*)(ws_diag + (size_t)n * 16);    // n ints
    float* ws_S    = (float*)(ws_cnt + n);                // n*16 floats
    float* ws_vd   = ws_S + (size_t)n * 16;               // n*16 floats
    float* ws_ve   = ws_vd + (size_t)n * 16;              // E*16 floats (2 MB)
    int*   ws_list = (int*)(ws_ve + (size_t)E * 16);      // n*MAXDEG ints

    hipMemsetAsync(ws_diag, 0,
                   (size_t)n * 16 * sizeof(float) + (size_t)n * sizeof(int),
                   stream);

    accum_diag_kernel<<<(twoE + 255) / 256, 256, 0, stream>>>(maps, ei, ws_diag, twoE);
    node_kernel<<<(n + 255) / 256, 256, 0, stream>>>(ws_diag, ws_S, ws_vd, n);
    edge_kernel<<<(E + 255) / 256, 256, 0, stream>>>(maps, ei, ws_S, ws_ve,
                                                     ws_list, ws_cnt, E, twoE);
    writer_kernel<<<n, 256, 0, stream>>>(ws_list, ws_cnt, ws_vd, ws_ve, out, ld);
}

// Round 4
// 94.847 us; speedup vs baseline: 2.2217x; 1.3496x over previous
//
#include <hip/hip_runtime.h>
#include <math.h>

// LaplacianBuilder: N=2048 nodes, DEG=16, D=4, E=32768 (2E=65536 directed)
// out = dense (8192 x 8192) fp32, 256 MB.
// v4: 3 kernels. (1) adjacency build (1 int atomic/directed edge),
// (2) per-node gather-Gram + eigh -> S + diag block (no fp atomics),
// (3) streaming writer with fused edge sandwich (no vedge round-trip).

#define NNODES 2048
#define MAXDEG 96   // per-node directed-degree capacity (mean 32, huge margin)

// ---------------------------------------------------------------------------
// K1: per directed edge e in [0,2E): append (col<<20 | t<<19 | u) to
// list[ei[0][e]].  t=1 for the reverse half (e>=E), u = undirected index.
// Same list drives Gram accumulation (maps[t?E+u:u]) and scatter (t=1 wins).
// ---------------------------------------------------------------------------
__global__ void build_lists_kernel(const int* __restrict__ ei,
                                   int* __restrict__ lists,
                                   int* __restrict__ cnts,
                                   int E, int twoE) {
    int e = blockIdx.x * blockDim.x + threadIdx.x;
    if (e >= twoE) return;
    int node = ei[e];
    int nbr = ei[twoE + e];
    int t = (e >= E) ? 1 : 0;
    int u = t ? (e - E) : e;
    int slot = atomicAdd(&cnts[node], 1);
    if (slot < MAXDEG)
        lists[(size_t)node * MAXDEG + slot] = (nbr << 20) | (t << 19) | u;
}

// ---------------------------------------------------------------------------
// Jacobi rotation on (P,Q), compile-time indices -> stays in registers
// ---------------------------------------------------------------------------
template <int P, int Q>
__device__ __forceinline__ void jrot(float a[4][4], float v[4][4]) {
    float apq = a[P][Q];
    if (fabsf(apq) < 1e-12f) return;
    float theta = (a[Q][Q] - a[P][P]) / (2.0f * apq);
    float t = 1.0f / (fabsf(theta) + sqrtf(theta * theta + 1.0f));
    t = (theta < 0.0f) ? -t : t;
    float c = 1.0f / sqrtf(t * t + 1.0f);
    float s = t * c;
    #pragma unroll
    for (int k = 0; k < 4; ++k) {
        float akp = a[k][P], akq = a[k][Q];
        a[k][P] = c * akp - s * akq;
        a[k][Q] = s * akp + c * akq;
    }
    #pragma unroll
    for (int k = 0; k < 4; ++k) {
        float apk = a[P][k], aqk = a[Q][k];
        a[P][k] = c * apk - s * aqk;
        a[Q][k] = s * apk + c * aqk;
    }
    #pragma unroll
    for (int k = 0; k < 4; ++k) {
        float vkp = v[k][P], vkq = v[k][Q];
        v[k][P] = c * vkp - s * vkq;
        v[k][Q] = s * vkp + c * vkq;
    }
}

// ---------------------------------------------------------------------------
// K2: per node (thread-per-node, 64-thread blocks for spread): gather-sum
// Gram over listed directed edges, eigh(G+I) via 6 Jacobi sweeps,
// S=(G+I)^(-1/2), vdiag = clip(S G S, -1, 1).
// ---------------------------------------------------------------------------
__global__ void __launch_bounds__(64)
node_kernel(const float* __restrict__ maps,
            const int* __restrict__ lists,
            const int* __restrict__ cnts,
            float* __restrict__ Smat,
            float* __restrict__ vdiag,
            int E, int n) {
    int node = blockIdx.x * blockDim.x + threadIdx.x;
    if (node >= n) return;
    float g[4][4];
    #pragma unroll
    for (int i = 0; i < 4; ++i)
        #pragma unroll
        for (int j = 0; j < 4; ++j) g[i][j] = 0.0f;
    int cnt = cnts[node];
    if (cnt > MAXDEG) cnt = MAXDEG;
    const int* myl = lists + (size_t)node * MAXDEG;
    #pragma unroll 4
    for (int j = 0; j < cnt; ++j) {
        int entry = myl[j];
        int t = (entry >> 19) & 1;
        int u = entry & 0x7FFF;
        int e = t ? (E + u) : u;
        const float4* mp = reinterpret_cast<const float4*>(maps + (size_t)e * 16);
        float4 q0 = mp[0], q1 = mp[1], q2 = mp[2], q3 = mp[3];
        float m[4][4] = {{q0.x, q0.y, q0.z, q0.w}, {q1.x, q1.y, q1.z, q1.w},
                         {q2.x, q2.y, q2.z, q2.w}, {q3.x, q3.y, q3.z, q3.w}};
        #pragma unroll
        for (int i = 0; i < 4; ++i)
            #pragma unroll
            for (int jj = 0; jj < 4; ++jj)
                g[i][jj] += m[0][i] * m[0][jj] + m[1][i] * m[1][jj] +
                            m[2][i] * m[2][jj] + m[3][i] * m[3][jj];
    }
    float a[4][4], v[4][4];
    #pragma unroll
    for (int i = 0; i < 4; ++i)
        #pragma unroll
        for (int j = 0; j < 4; ++j) {
            a[i][j] = g[i][j] + (i == j ? 1.0f : 0.0f);
            v[i][j] = (i == j) ? 1.0f : 0.0f;
        }
    #pragma unroll
    for (int sweep = 0; sweep < 6; ++sweep) {
        jrot<0, 1>(a, v); jrot<0, 2>(a, v); jrot<0, 3>(a, v);
        jrot<1, 2>(a, v); jrot<1, 3>(a, v); jrot<2, 3>(a, v);
    }
    float ir[4];
    #pragma unroll
    for (int m = 0; m < 4; ++m)
        ir[m] = 1.0f / sqrtf(fmaxf(a[m][m], 1e-8f));
    float s[4][4];
    #pragma unroll
    for (int i = 0; i < 4; ++i)
        #pragma unroll
        for (int j = 0; j < 4; ++j)
            s[i][j] = v[i][0] * v[j][0] * ir[0] + v[i][1] * v[j][1] * ir[1] +
                      v[i][2] * v[j][2] * ir[2] + v[i][3] * v[j][3] * ir[3];
    float4* sp = reinterpret_cast<float4*>(Smat + (size_t)node * 16);
    sp[0] = make_float4(s[0][0], s[0][1], s[0][2], s[0][3]);
    sp[1] = make_float4(s[1][0], s[1][1], s[1][2], s[1][3]);
    sp[2] = make_float4(s[2][0], s[2][1], s[2][2], s[2][3]);
    sp[3] = make_float4(s[3][0], s[3][1], s[3][2], s[3][3]);
    float t1[4][4];
    #pragma unroll
    for (int i = 0; i < 4; ++i)
        #pragma unroll
        for (int j = 0; j < 4; ++j)
            t1[i][j] = s[i][0] * g[0][j] + s[i][1] * g[1][j] +
                       s[i][2] * g[2][j] + s[i][3] * g[3][j];
    float4* vp = reinterpret_cast<float4*>(vdiag + (size_t)node * 16);
    #pragma unroll
    for (int i = 0; i < 4; ++i) {
        float r0 = t1[i][0] * s[0][0] + t1[i][1] * s[1][0] + t1[i][2] * s[2][0] + t1[i][3] * s[3][0];
        float r1 = t1[i][0] * s[0][1] + t1[i][1] * s[1][1] + t1[i][2] * s[2][1] + t1[i][3] * s[3][1];
        float r2 = t1[i][0] * s[0][2] + t1[i][1] * s[1][2] + t1[i][2] * s[2][2] + t1[i][3] * s[3][2];
        float r3 = t1[i][0] * s[0][3] + t1[i][1] * s[1][3] + t1[i][2] * s[2][3] + t1[i][3] * s[3][3];
        vp[i] = make_float4(fminf(fmaxf(r0, -1.0f), 1.0f),
                            fminf(fmaxf(r1, -1.0f), 1.0f),
                            fminf(fmaxf(r2, -1.0f), 1.0f),
                            fminf(fmaxf(r3, -1.0f), 1.0f));
    }
}

// ---------------------------------------------------------------------------
// K3: streaming writer with fused sandwich. One workgroup per block-row r.
// Threads tid<cnt each compute W = -clip(S_row (A^T B) S_col, -1, 1) for one
// listed edge (t=1 -> store W^T rows), build LDS colmap (t=0 then t=1 wins),
// then all 256 threads stream 4 x 8192 floats with O(1) LDS lookup.
// ---------------------------------------------------------------------------
__global__ void __launch_bounds__(256)
writer_kernel(const float* __restrict__ maps,
              const int* __restrict__ lists,
              const int* __restrict__ cnts,
              const float* __restrict__ Smat,
              const float* __restrict__ vdiag,
              float* __restrict__ out, int E, int ld) {
    int r = blockIdx.x;
    int tid = threadIdx.x;
    __shared__ int colmap[NNODES];             // 8 KB
    __shared__ float4 s_dat[MAXDEG + 1][4];    // ~6.2 KB
    for (int i = tid; i < NNODES; i += 256) colmap[i] = -1;

    int cnt = cnts[r];
    if (cnt > MAXDEG) cnt = MAXDEG;
    int col = -1, t = 0;
    if (tid < cnt) {
        int entry = lists[(size_t)r * MAXDEG + tid];
        col = entry >> 20;
        t = (entry >> 19) & 1;
        int u = entry & 0x7FFF;
        const float4* ap = reinterpret_cast<const float4*>(maps + (size_t)u * 16);
        const float4* bp = reinterpret_cast<const float4*>(maps + (size_t)(E + u) * 16);
        float4 a0 = ap[0], a1 = ap[1], a2 = ap[2], a3 = ap[3];
        float4 b0 = bp[0], b1 = bp[1], b2 = bp[2], b3 = bp[3];
        float A[4][4] = {{a0.x, a0.y, a0.z, a0.w}, {a1.x, a1.y, a1.z, a1.w},
                         {a2.x, a2.y, a2.z, a2.w}, {a3.x, a3.y, a3.z, a3.w}};
        float B[4][4] = {{b0.x, b0.y, b0.z, b0.w}, {b1.x, b1.y, b1.z, b1.w},
                         {b2.x, b2.y, b2.z, b2.w}, {b3.x, b3.y, b3.z, b3.w}};
        float C[4][4];
        #pragma unroll
        for (int i = 0; i < 4; ++i)
            #pragma unroll
            for (int j = 0; j < 4; ++j)
                C[i][j] = A[0][i] * B[0][j] + A[1][i] * B[1][j] +
                          A[2][i] * B[2][j] + A[3][i] * B[3][j];
        int rn = t ? col : r;   // row[u]
        int cn = t ? r : col;   // col[u]
        const float4* srp = reinterpret_cast<const float4*>(Smat + (size_t)rn * 16);
        const float4* scp = reinterpret_cast<const float4*>(Smat + (size_t)cn * 16);
        float4 s0 = srp[0], s1 = srp[1], s2 = srp[2], s3 = srp[3];
        float Sr[4][4] = {{s0.x, s0.y, s0.z, s0.w}, {s1.x, s1.y, s1.z, s1.w},
                          {s2.x, s2.y, s2.z, s2.w}, {s3.x, s3.y, s3.z, s3.w}};
        float4 c0 = scp[0], c1 = scp[1], c2 = scp[2], c3 = scp[3];
        float Sc[4][4] = {{c0.x, c0.y, c0.z, c0.w}, {c1.x, c1.y, c1.z, c1.w},
                          {c2.x, c2.y, c2.z, c2.w}, {c3.x, c3.y, c3.z, c3.w}};
        float t1m[4][4];
        #pragma unroll
        for (int i = 0; i < 4; ++i)
            #pragma unroll
            for (int j = 0; j < 4; ++j)
                t1m[i][j] = Sr[i][0] * C[0][j] + Sr[i][1] * C[1][j] +
                            Sr[i][2] * C[2][j] + Sr[i][3] * C[3][j];
        float W[4][4];
        #pragma unroll
        for (int i = 0; i < 4; ++i)
            #pragma unroll
            for (int j = 0; j < 4; ++j) {
                float x = t1m[i][0] * Sc[0][j] + t1m[i][1] * Sc[1][j] +
                          t1m[i][2] * Sc[2][j] + t1m[i][3] * Sc[3][j];
                W[i][j] = -fminf(fmaxf(x, -1.0f), 1.0f);
            }
        if (t) {   // block (r,col) = W^T
            s_dat[tid][0] = make_float4(W[0][0], W[1][0], W[2][0], W[3][0]);
            s_dat[tid][1] = make_float4(W[0][1], W[1][1], W[2][1], W[3][1]);
            s_dat[tid][2] = make_float4(W[0][2], W[1][2], W[2][2], W[3][2]);
            s_dat[tid][3] = make_float4(W[0][3], W[1][3], W[2][3], W[3][3]);
        } else {
            s_dat[tid][0] = make_float4(W[0][0], W[0][1], W[0][2], W[0][3]);
            s_dat[tid][1] = make_float4(W[1][0], W[1][1], W[1][2], W[1][3]);
            s_dat[tid][2] = make_float4(W[2][0], W[2][1], W[2][2], W[2][3]);
            s_dat[tid][3] = make_float4(W[3][0], W[3][1], W[3][2], W[3][3]);
        }
    }
    if (tid < 4)
        s_dat[MAXDEG][tid] = reinterpret_cast<const float4*>(vdiag + (size_t)r * 16)[tid];
    __syncthreads();                           // colmap cleared + s_dat ready
    if (tid < cnt && !t) colmap[col] = tid;
    __syncthreads();                           // t=0 placed
    if (tid < cnt && t) colmap[col] = tid;     // t=1 wins (reference order)
    if (tid == 0) colmap[r] = MAXDEG;          // diag (no self-edges)
    __syncthreads();

    size_t base = (size_t)(r * 4) * (size_t)ld;
    const float4 zero = make_float4(0.f, 0.f, 0.f, 0.f);
    #pragma unroll
    for (int ri = 0; ri < 4; ++ri) {
        float4* orow = reinterpret_cast<float4*>(out + base + (size_t)ri * ld);
        for (int cb = tid; cb < NNODES; cb += 256) {
            int sl = colmap[cb];
            float4 val = zero;
            if (sl >= 0) val = s_dat[sl][ri];
            orow[cb] = val;
        }
    }
}

extern "C" void kernel_launch(void* const* d_in, const int* in_sizes, int n_in,
                              void* d_out, int out_size, void* d_ws, size_t ws_size,
                              hipStream_t stream) {
    const float* maps = (const float*)d_in[0];
    const int* ei = (const int*)d_in[1];   // (2, 2E) int32
    int twoE = in_sizes[0] / 16;           // 65536
    int E = twoE / 2;                      // 32768
    const int n = NNODES;
    const int ld = n * 4;                  // 8192
    float* out = (float*)d_out;

    int*   ws_cnt  = (int*)d_ws;                          // n ints
    int*   ws_list = ws_cnt + n;                          // n*MAXDEG ints
    float* ws_S    = (float*)(ws_list + (size_t)n * MAXDEG); // n*16 floats
    float* ws_vd   = ws_S + (size_t)n * 16;               // n*16 floats

    hipMemsetAsync(ws_cnt, 0, (size_t)n * sizeof(int), stream);

    build_lists_kernel<<<(twoE + 255) / 256, 256, 0, stream>>>(ei, ws_list, ws_cnt, E, twoE);
    node_kernel<<<(n + 63) / 64, 64, 0, stream>>>(maps, ws_list, ws_cnt, ws_S, ws_vd, E, n);
    writer_kernel<<<n, 256, 0, stream>>>(maps, ws_list, ws_cnt, ws_S, ws_vd, out, E, ld);
}